// Round 4
// baseline (525.154 us; speedup 1.0000x reference)
//
#include <hip/hip_runtime.h>

#define BB 256
#define SS 2048
#define FF 64
#define NBB 32
#define NCH 16            // chunks over t
#define CHT 128           // t per chunk
#define NSUB (SS/16)      // 128 sub-iters of 16 t
#define WAVES_TOTAL 1024  // 256 producer blocks x 4 waves

// 2*log2(e): folded into u so the scan's tanh needs only exp2 on the chain
#define TWO_OVER_LN2 2.885390081777927f

// ---------------------------------------------------------------------------
// Fused producer-consumer kernel.
//  block 0            : consumer — the serial scan, lane = batch (256 lanes).
//  blocks 1..256      : producer for batch b = blockIdx.x-1. Computes
//                       u[b][t] = 2log2e*(dot(X[b,t,:],W_ih)+b_ih+b_hh) + w',
//                       tf[b][t] = X[b,t,1]; publishes per-chunk (128 t) via
//                       per-wave release atomicAdd (target 1024/chunk).
// Consumer invariant: before processing chunk c, chunks <= c+1 are flagged, so
// the distance-2 sub-iter prefetch (32 t ahead) never outruns published data.
// 257 blocks x 4 waves << chip capacity -> all co-resident, no deadlock.
// ---------------------------------------------------------------------------

#define LOADB(N, s) { int q_ = ((s) < NSUB ? (s) : (NSUB-1)) * 4; \
    N##_0 = ub[q_+0]; N##_1 = ub[q_+1]; N##_2 = ub[q_+2]; N##_3 = ub[q_+3]; }

#define STEP(c) { \
    float z = fmaf(m2w, r, (c)); \
    float y = __builtin_amdgcn_exp2f(z); \
    r = __builtin_amdgcn_rcpf(y + 1.0f); \
    *op = fmaf(-2.0f, r, 1.0f); op += BB; }

#define PROCB(N) { \
    STEP(N##_0.x) STEP(N##_0.y) STEP(N##_0.z) STEP(N##_0.w) \
    STEP(N##_1.x) STEP(N##_1.y) STEP(N##_1.z) STEP(N##_1.w) \
    STEP(N##_2.x) STEP(N##_2.y) STEP(N##_2.z) STEP(N##_2.w) \
    STEP(N##_3.x) STEP(N##_3.y) STEP(N##_3.z) STEP(N##_3.w) }

// poll with RMW (an atomic *load* could hit a stale local-L2 copy); acquire
// orders the subsequent u loads after the producer's release.
#define WAITC(c) if ((c) < NCH) { \
    int done_ = 0; \
    while (!done_) { \
        int v_ = 0; \
        if ((threadIdx.x & 63) == 0) \
            v_ = __hip_atomic_fetch_add(&cnt[(c)], 0, __ATOMIC_ACQUIRE, \
                                        __HIP_MEMORY_SCOPE_AGENT); \
        v_ = __shfl(v_, 0); \
        done_ = (v_ >= WAVES_TOTAL); \
    } }

// 8 sub-iters (one 128-t chunk), 3-buffer rotation, prefetch distance 2.
// Entry: P0 holds sub-iter c*8, P1 holds c*8+1. Exit state rotated by 2.
#define CHUNK(P0, P1, P2, c) { \
    WAITC((c)+2) \
    LOADB(P2, (c)*8+2) PROCB(P0) \
    LOADB(P0, (c)*8+3) PROCB(P1) \
    LOADB(P1, (c)*8+4) PROCB(P2) \
    LOADB(P2, (c)*8+5) PROCB(P0) \
    LOADB(P0, (c)*8+6) PROCB(P1) \
    LOADB(P1, (c)*8+7) PROCB(P2) \
    LOADB(P2, (c)*8+8) PROCB(P0) \
    LOADB(P0, (c)*8+9) PROCB(P1) }

__global__ __launch_bounds__(256) void k_fused(
    const float* __restrict__ X, const float* __restrict__ W_ih,
    const float* __restrict__ b_ih, const float* __restrict__ b_hh,
    const float* __restrict__ W_hh, const float* __restrict__ hx0,
    float* __restrict__ u, float* __restrict__ tf,
    int* __restrict__ cnt, float* __restrict__ out_h)
{
    if (blockIdx.x == 0) {
        // ---------------- consumer: serial scan ----------------
        const int b = threadIdx.x;                 // batch = lane
        const float wp  = W_hh[0] * TWO_OVER_LN2;
        const float m2w = -2.0f * wp;
        float r = 0.5f * (1.0f - hx0[b]);          // 1-2r == hx0
        const float4* ub = reinterpret_cast<const float4*>(u + (size_t)b * SS);
        float* op = out_h + b;

        float4 A_0,A_1,A_2,A_3, B_0,B_1,B_2,B_3, C_0,C_1,C_2,C_3;
        WAITC(0) WAITC(1)
        LOADB(A, 0)
        LOADB(B, 1)

        int c = 0;
        #pragma unroll 1
        for (int g = 0; g < 5; ++g) {              // 15 chunks
            CHUNK(A, B, C, c) c++;
            CHUNK(C, A, B, c) c++;
            CHUNK(B, C, A, c) c++;
        }
        CHUNK(A, B, C, 15)                          // chunk 15 (waits skipped)
    } else {
        // ---------------- producer: projection ----------------
        const int b = blockIdx.x - 1;
        const int g = threadIdx.x >> 4;            // row-group 0..15
        const int l = threadIdx.x & 15;
        const float4 w = reinterpret_cast<const float4*>(W_ih)[l];
        const float bias = b_ih[0] + b_hh[0];
        const float wp = W_hh[0] * TWO_OVER_LN2;
        const float4* Xb = reinterpret_cast<const float4*>(X + (size_t)b * SS * FF);
        float* ubp = u + (size_t)b * SS;
        float* tbp = tf + (size_t)b * SS;

        #pragma unroll 1
        for (int c = 0; c < NCH; ++c) {
            const int t0 = c * CHT + g;
            float4 v[8];
            #pragma unroll
            for (int i = 0; i < 8; ++i)
                v[i] = Xb[(size_t)(t0 + 16*i) * 16 + l];
            #pragma unroll
            for (int i = 0; i < 8; ++i) {
                float p = v[i].x*w.x + v[i].y*w.y + v[i].z*w.z + v[i].w*w.w;
                p += __shfl_xor(p, 1);
                p += __shfl_xor(p, 2);
                p += __shfl_xor(p, 4);
                p += __shfl_xor(p, 8);
                if (l == 0) {
                    ubp[t0 + 16*i] = TWO_OVER_LN2 * (p + bias) + wp;
                    tbp[t0 + 16*i] = v[i].y;
                }
            }
            // per-WAVE release (no __syncthreads -> other waves keep streaming)
            if ((threadIdx.x & 63) == 0)
                __hip_atomic_fetch_add(&cnt[c], 1, __ATOMIC_RELEASE,
                                       __HIP_MEMORY_SCOPE_AGENT);
        }
    }
}

// ---------------------------------------------------------------------------
// K3: lam[t][b] = softplus( sum_j relu( (hx*W2e_j+be_j)*t + (hx*W2o_j+bo_j) ) )
// ---------------------------------------------------------------------------
__global__ __launch_bounds__(256) void k_lam(
    const float* __restrict__ tf, const float* __restrict__ W_h2p,
    const float* __restrict__ b_h2p, const float* __restrict__ hid,
    float* __restrict__ lam)
{
    __shared__ float4 cb[NBB];
    if (threadIdx.x < NBB) {
        int j = threadIdx.x;
        cb[j] = make_float4(W_h2p[2*j], W_h2p[2*j+1], b_h2p[2*j], b_h2p[2*j+1]);
    }
    __syncthreads();

    const int bi = threadIdx.x;
    const int t0 = blockIdx.x * 8;

    float hx[8], tt[8], s[8];
    {
        const float4* tb = reinterpret_cast<const float4*>(tf + (size_t)bi * SS + t0);
        float4 ta = tb[0], tc = tb[1];
        tt[0]=ta.x; tt[1]=ta.y; tt[2]=ta.z; tt[3]=ta.w;
        tt[4]=tc.x; tt[5]=tc.y; tt[6]=tc.z; tt[7]=tc.w;
    }
    #pragma unroll
    for (int k = 0; k < 8; ++k) {
        hx[k] = hid[(size_t)(t0 + k) * BB + bi];
        s[k] = 0.0f;
    }
    for (int j = 0; j < NBB; ++j) {
        const float4 c = cb[j];
        #pragma unroll
        for (int k = 0; k < 8; ++k) {
            float alpha = fmaf(hx[k], c.x, c.z);
            float beta  = fmaf(hx[k], c.y, c.w);
            s[k] += fmaxf(fmaf(alpha, tt[k], beta), 0.0f);
        }
    }
    #pragma unroll
    for (int k = 0; k < 8; ++k) {
        float v  = s[k];
        float as = fabsf(v);
        float e  = __builtin_amdgcn_exp2f(-as * 1.4426950408889634f);
        float l  = __builtin_amdgcn_logf(1.0f + e) * 0.6931471805599453f;
        lam[(size_t)(t0 + k) * BB + bi] = fmaxf(v, 0.0f) + l;
    }
}

// ---------------------------------------------------------------------------
extern "C" void kernel_launch(void* const* d_in, const int* in_sizes, int n_in,
                              void* d_out, int out_size, void* d_ws, size_t ws_size,
                              hipStream_t stream) {
    const float* X     = (const float*)d_in[0];
    const float* hx0   = (const float*)d_in[1];
    const float* W_ih  = (const float*)d_in[2];
    const float* b_ih  = (const float*)d_in[3];
    const float* W_hh  = (const float*)d_in[4];
    const float* b_hh  = (const float*)d_in[5];
    const float* W_h2p = (const float*)d_in[6];
    const float* b_h2p = (const float*)d_in[7];

    float* out_h = (float*)d_out;                 // hidden_states (S,B,1) [t][b]
    float* out_l = out_h + (size_t)SS * BB;       // intensity     (S,B)   [t][b]
    float* u  = (float*)d_ws;                     // u'' [B][S], 2 MiB
    float* tf = u + (size_t)BB * SS;              // X[:,:,1] compacted, 2 MiB
    int*  cnt = (int*)(tf + (size_t)BB * SS);     // NCH chunk counters

    hipMemsetAsync(cnt, 0, NCH * sizeof(int), stream);   // deterministic flags
    k_fused<<<257, 256, 0, stream>>>(X, W_ih, b_ih, b_hh, W_hh, hx0,
                                     u, tf, cnt, out_h);
    k_lam<<<SS / 8, 256, 0, stream>>>(tf, W_h2p, b_h2p, out_h, out_l);
}

// Round 5
// 49.706 us; speedup vs baseline: 10.5653x; 10.5653x over previous
//
#include <hip/hip_runtime.h>

#define BB 256
#define SS 2048
#define FF 64
#define NBB 32

#define PL 64             // output timesteps per scan partition
#define NP (SS/PL)        // 32 partitions
#define WUP 384           // speculative warm-up steps (forgetting ~e^-300)

// 2*log2(e): folded into u so the scan's tanh needs only exp2 on the chain
#define TWO_OVER_LN2 2.885390081777927f

// ---------------------------------------------------------------------------
// K1: u[t4-layout] = 2log2e*(dot(X[b,t,:],W_ih)+b_ih+b_hh) + 2log2e*W_hh
//     tf[t4-layout] = X[b,t,1]
// t4 layout: elem (b,t) lives at ((t>>2)*BB + b)*4 + (t&3)  -> the scan and
// k_lam read it as float4[(t>>2)*BB + b] (coalesced 16B/lane).
// Reads of X are fully coalesced float4 (the HBM-bound part, 128 MiB).
// ---------------------------------------------------------------------------
__global__ __launch_bounds__(256) void k_proj(
    const float* __restrict__ X, const float* __restrict__ W_ih,
    const float* __restrict__ b_ih, const float* __restrict__ b_hh,
    const float* __restrict__ W_hh,
    float* __restrict__ u4, float* __restrict__ tf4)
{
    const int l = threadIdx.x & 15;
    const int group  = (blockIdx.x * blockDim.x + threadIdx.x) >> 4;
    const int ngroups = (gridDim.x * blockDim.x) >> 4;
    const float4 w = reinterpret_cast<const float4*>(W_ih)[l];
    const float bias = b_ih[0] + b_hh[0];
    const float wp = W_hh[0] * TWO_OVER_LN2;
    const int nrows = BB * SS;
    for (int r = group; r < nrows; r += ngroups) {
        const float4 v = reinterpret_cast<const float4*>(X + (size_t)r * FF)[l];
        float p = v.x * w.x + v.y * w.y + v.z * w.z + v.w * w.w;
        p += __shfl_xor(p, 1);
        p += __shfl_xor(p, 2);
        p += __shfl_xor(p, 4);
        p += __shfl_xor(p, 8);
        if (l == 0) {
            const int b = r >> 11;          // r / SS
            const int t = r & (SS - 1);
            const int idx = ((t >> 2) * BB + b) * 4 + (t & 3);
            u4[idx]  = TWO_OVER_LN2 * (p + bias) + wp;
            tf4[idx] = v.y;
        }
    }
}

// ---------------------------------------------------------------------------
// K2: speculative blocked scan. block = partition p (32), thread = batch b.
// Each thread runs the recurrence from t_s = max(0, p*PL - WUP); partitions
// reaching t=0 start from the true hx0 (exact), others from hx=0 and rely on
// the recurrence's exponential forgetting (warm-up residual ~e^-300 expected).
// Chain per step: r = rcp(1 + exp2(fma(m2w, r, u''))) ; hx = 1-2r off-chain.
// u read as coalesced float4 per 4 steps, software-pipelined 8 quads ahead.
// ---------------------------------------------------------------------------
__global__ __launch_bounds__(256) void k_scan(
    const float* __restrict__ u4, const float* __restrict__ hx0,
    const float* __restrict__ W_hh, float* __restrict__ out_h)
{
    const int b = threadIdx.x;
    const int p = blockIdx.x;
    const float m2w = -2.0f * (W_hh[0] * TWO_OVER_LN2);

    int t_s = p * PL - WUP;
    float r;
    if (t_s <= 0) { t_s = 0; r = 0.5f * (1.0f - hx0[b]); }   // exact start
    else          { r = 0.5f; }                               // neutral (hx=0)

    const float4* U = reinterpret_cast<const float4*>(u4);
    const int q0   = t_s >> 2;
    const int q1   = ((p + 1) * PL) >> 2;     // q1-q0 is a multiple of 8
    const int qout = (p * PL) >> 2;           // first quad that emits output

    float4 buf[8];
    #pragma unroll
    for (int i = 0; i < 8; ++i) {
        int q = q0 + i; if (q > q1 - 1) q = q1 - 1;
        buf[i] = U[(size_t)q * BB + b];
    }

    #pragma unroll 1
    for (int q = q0; q < q1; q += 8) {
        #pragma unroll
        for (int i = 0; i < 8; ++i) {
            const int qq = q + i;
            const float4 c = buf[i];
            float z0 = fmaf(m2w, r, c.x);
            float y0 = __builtin_amdgcn_exp2f(z0);
            r = __builtin_amdgcn_rcpf(y0 + 1.0f);
            if (qq >= qout) out_h[(size_t)(qq*4+0)*BB + b] = fmaf(-2.0f, r, 1.0f);
            float z1 = fmaf(m2w, r, c.y);
            float y1 = __builtin_amdgcn_exp2f(z1);
            r = __builtin_amdgcn_rcpf(y1 + 1.0f);
            if (qq >= qout) out_h[(size_t)(qq*4+1)*BB + b] = fmaf(-2.0f, r, 1.0f);
            float z2 = fmaf(m2w, r, c.z);
            float y2 = __builtin_amdgcn_exp2f(z2);
            r = __builtin_amdgcn_rcpf(y2 + 1.0f);
            if (qq >= qout) out_h[(size_t)(qq*4+2)*BB + b] = fmaf(-2.0f, r, 1.0f);
            float z3 = fmaf(m2w, r, c.w);
            float y3 = __builtin_amdgcn_exp2f(z3);
            r = __builtin_amdgcn_rcpf(y3 + 1.0f);
            if (qq >= qout) out_h[(size_t)(qq*4+3)*BB + b] = fmaf(-2.0f, r, 1.0f);
            int qn = qq + 8; if (qn > q1 - 1) qn = q1 - 1;    // refill (depth 8)
            buf[i] = U[(size_t)qn * BB + b];
        }
    }
}

// ---------------------------------------------------------------------------
// K3: lam[t][b] = softplus( sum_j relu( (hx*W2e_j+be_j)*t + (hx*W2o_j+bo_j) ) )
// thread = b, block covers 8 consecutive t. tf read as two float4 (t4 layout).
// ---------------------------------------------------------------------------
__global__ __launch_bounds__(256) void k_lam(
    const float* __restrict__ tf4, const float* __restrict__ W_h2p,
    const float* __restrict__ b_h2p, const float* __restrict__ hid,
    float* __restrict__ lam)
{
    __shared__ float4 cb[NBB];
    if (threadIdx.x < NBB) {
        int j = threadIdx.x;
        cb[j] = make_float4(W_h2p[2*j], W_h2p[2*j+1], b_h2p[2*j], b_h2p[2*j+1]);
    }
    __syncthreads();

    const int bi = threadIdx.x;
    const int t0 = blockIdx.x * 8;

    float hx[8], tt[8], s[8];
    {
        const float4* F = reinterpret_cast<const float4*>(tf4);
        float4 ta = F[(size_t)(t0 >> 2) * BB + bi];
        float4 tc = F[(size_t)((t0 >> 2) + 1) * BB + bi];
        tt[0]=ta.x; tt[1]=ta.y; tt[2]=ta.z; tt[3]=ta.w;
        tt[4]=tc.x; tt[5]=tc.y; tt[6]=tc.z; tt[7]=tc.w;
    }
    #pragma unroll
    for (int k = 0; k < 8; ++k) {
        hx[k] = hid[(size_t)(t0 + k) * BB + bi];
        s[k] = 0.0f;
    }
    for (int j = 0; j < NBB; ++j) {
        const float4 c = cb[j];
        #pragma unroll
        for (int k = 0; k < 8; ++k) {
            float alpha = fmaf(hx[k], c.x, c.z);
            float beta  = fmaf(hx[k], c.y, c.w);
            s[k] += fmaxf(fmaf(alpha, tt[k], beta), 0.0f);
        }
    }
    #pragma unroll
    for (int k = 0; k < 8; ++k) {
        float v  = s[k];
        float as = fabsf(v);
        float e  = __builtin_amdgcn_exp2f(-as * 1.4426950408889634f);
        float l  = __builtin_amdgcn_logf(1.0f + e) * 0.6931471805599453f;
        lam[(size_t)(t0 + k) * BB + bi] = fmaxf(v, 0.0f) + l;
    }
}

// ---------------------------------------------------------------------------
extern "C" void kernel_launch(void* const* d_in, const int* in_sizes, int n_in,
                              void* d_out, int out_size, void* d_ws, size_t ws_size,
                              hipStream_t stream) {
    const float* X     = (const float*)d_in[0];
    const float* hx0   = (const float*)d_in[1];
    const float* W_ih  = (const float*)d_in[2];
    const float* b_ih  = (const float*)d_in[3];
    const float* W_hh  = (const float*)d_in[4];
    const float* b_hh  = (const float*)d_in[5];
    const float* W_h2p = (const float*)d_in[6];
    const float* b_h2p = (const float*)d_in[7];

    float* out_h = (float*)d_out;                 // hidden_states (S,B,1) [t][b]
    float* out_l = out_h + (size_t)SS * BB;       // intensity     (S,B)   [t][b]
    float* u4  = (float*)d_ws;                    // u'' t4-layout, 2 MiB
    float* tf4 = u4 + (size_t)BB * SS;            // X[:,:,1] t4-layout, 2 MiB

    k_proj<<<2048, 256, 0, stream>>>(X, W_ih, b_ih, b_hh, W_hh, u4, tf4);
    k_scan<<<NP, 256, 0, stream>>>(u4, hx0, W_hh, out_h);
    k_lam<<<SS / 8, 256, 0, stream>>>(tf4, W_h2p, b_h2p, out_h, out_l);
}